// Round 18
// baseline (800.599 us; speedup 1.0000x reference)
//
#include <hip/hip_runtime.h>
#include <hip/hip_bf16.h>

// InputProjection: LN folded INTO the GEMM (fp32 in, fp32 out).
// q = rstd*(x @ (gamma.*W)^T) - (rstd*mu)*c1 + (c2 + b),
//   c1[n] = sum_k gamma_k*W[n,k], c2[n] = sum_k beta_k*W[n,k].
// R18 = R11's exact K-loop skeleton (8 phases, 4 regions [2buf][2kk],
// 16-MFMA phases, setprio, pipelined RD) with reg-staged A (fp32 x ->
// cvt_pk bf16 -> LDS) and reg-staged B (T14 split: loads 2 phases early,
// writes at slot; all waits compiler-managed -> NO manual vmcnt).
// Per-row LN stats accumulated during A-staging; applied in epilogue.

#define HIDDEN 1024
#define NTOK   32768

typedef __bf16 bf16x8 __attribute__((ext_vector_type(8)));
typedef float  f32x4  __attribute__((ext_vector_type(4)));

__device__ __forceinline__ float bf2f(unsigned short u) {
  union { unsigned int i; float f; } x; x.i = ((unsigned int)u) << 16; return x.f;
}
__device__ __forceinline__ unsigned short f2bf(float f) {
  union { float f; unsigned int i; } x; x.f = f;
  unsigned int r = x.i + 0x7FFFu + ((x.i >> 16) & 1u);   // RNE
  return (unsigned short)(r >> 16);
}
__device__ __forceinline__ unsigned int cvtpk(float lo, float hi) {
  unsigned int r;
  asm volatile("v_cvt_pk_bf16_f32 %0, %1, %2" : "=v"(r) : "v"(lo), "v"(hi));
  return r;
}

// ---------------- K1: gamma-folded weight cvt + c1/c2 ----------------
// 1536 blocks (one per output column n), 256 threads.
__global__ __launch_bounds__(256) void cvt_c12(
    const float* __restrict__ wq, const float* __restrict__ wk,
    const float* __restrict__ wv, const float* __restrict__ gamma,
    const float* __restrict__ beta, unsigned short* __restrict__ wb,
    float* __restrict__ c1, float* __restrict__ c2) {
  const int n = blockIdx.x, t = threadIdx.x;
  const float* src; int roff;
  if (n < 1024)      { src = wq; roff = n; }
  else if (n < 1280) { src = wk; roff = n - 1024; }
  else               { src = wv; roff = n - 1280; }
  const float4 w4 = ((const float4*)(src + (size_t)roff * HIDDEN))[t];
  const float4 g4 = ((const float4*)gamma)[t];
  const float4 b4 = ((const float4*)beta)[t];
  ushort4 o;
  o.x = f2bf(w4.x * g4.x); o.y = f2bf(w4.y * g4.y);
  o.z = f2bf(w4.z * g4.z); o.w = f2bf(w4.w * g4.w);
  ((ushort4*)(wb + (size_t)n * HIDDEN))[t] = o;
  // c1 from the ROUNDED weights (matches what MFMA consumes); c2 from raw W.
  float c1p = bf2f(o.x) + bf2f(o.y) + bf2f(o.z) + bf2f(o.w);
  float c2p = b4.x * w4.x + b4.y * w4.y + b4.z * w4.z + b4.w * w4.w;
#pragma unroll
  for (int off = 32; off >= 1; off >>= 1) {
    c1p += __shfl_xor(c1p, off);
    c2p += __shfl_xor(c2p, off);
  }
  __shared__ float red[8];
  const int w = t >> 6;
  if ((t & 63) == 0) { red[w] = c1p; red[4 + w] = c2p; }
  __syncthreads();
  if (t == 0) {
    c1[n] = red[0] + red[1] + red[2] + red[3];
    c2[n] = red[4] + red[5] + red[6] + red[7];
  }
}

// ---------------- K2: fused LN+QKV GEMM ----------------
// 768 blocks (128 M x 6 N), 512 threads (8 waves, 2M x 4N), wave tile 128x64.
__global__ __launch_bounds__(512, 2) void qkv_gemm(
    const float* __restrict__ x,
    const unsigned short* __restrict__ wqb,
    const float* __restrict__ c1g,
    const float* __restrict__ c2g,
    const float* __restrict__ bq,
    const float* __restrict__ bk,
    const float* __restrict__ bv,
    float* __restrict__ out) {
  __shared__ unsigned short Alds[32768];   // [2buf][2kk][256][32] bf16
  __shared__ unsigned short Blds[32768];
  __shared__ float2 statsL[256];           // per-row (sum, sumsq)

  const int bid = blockIdx.x;
  const int swz = (bid & 7) * 96 + (bid >> 3);   // bijective: 768 % 8 == 0
  const int mt  = swz / 6;
  const int nt  = swz % 6;
  const int brow = mt * 256;

  const unsigned short* wbase; const float* biasptr;
  int segcol; size_t obase; int hg; int nbase;
  if (nt < 4)       { wbase = wqb + (size_t)nt * 256 * HIDDEN;  biasptr = bq; segcol = nt * 256; obase = 0u;        hg = 16; nbase = 0; }
  else if (nt == 4) { wbase = wqb + (size_t)1024 * HIDDEN;      biasptr = bk; segcol = 0;        obase = 33554432u; hg = 4;  nbase = 1024; }
  else              { wbase = wqb + (size_t)1280 * HIDDEN;      biasptr = bv; segcol = 0;        obase = 41943040u; hg = 4;  nbase = 1280; }

  const int t = threadIdx.x;
  const int w = t >> 6, lane = t & 63;
  const int wm = w >> 2, wn = w & 3;
  const int l15 = lane & 15, hi = lane >> 4;

  // A reg-stage: lane covers row 32w + q*8 + (lane>>3), cols (lane&7)*4..+4
  const float* aRow = x + (size_t)(brow + 32 * w + (lane >> 3)) * HIDDEN + (lane & 7) * 4;
  // B reg-stage: lane covers row 32w + p*16 + (lane>>2), cols (lane&3)*8..+8
  const unsigned short* bRow = wbase + (size_t)(32 * w + (lane >> 2)) * HIDDEN + (lane & 3) * 8;
  // LDS write offsets (elems), granule-swizzled to match RD (LDS[g']=src[g'^s])
  const int aw0 = (32 * w + (lane >> 3)) * 32 + ((((lane & 7) >> 1) ^ (lane >> 4)) * 8) + (lane & 1) * 4;
  const int bw0 = (32 * w + (lane >> 2)) * 32 + (((lane & 3) ^ ((lane >> 3) & 3)) * 8);

  // ds_read (R11-proven): addr = reg*8192 + row*32 + (hi ^ ((row>>1)&3))*8
  const int rdx  = (hi ^ ((l15 >> 1) & 3)) * 8;
  const int rowA = wm * 128 + l15;
  const int rowB = wn * 64  + l15;

  f32x4 acc[8][4];
#pragma unroll
  for (int m = 0; m < 8; ++m)
#pragma unroll
    for (int n = 0; n < 4; ++n) acc[m][n] = (f32x4){0.f, 0.f, 0.f, 0.f};
  bf16x8 a0[8], a1[8], b0[4], b1[4];
  float4 xA[4], xB[4];
  bf16x8 bA[2], bB[2];
  float sq[4]  = {0.f, 0.f, 0.f, 0.f};
  float s2q[4] = {0.f, 0.f, 0.f, 0.f};

#define ALD(SET, COL) do { _Pragma("unroll")                                    \
    for (int q = 0; q < 4; ++q)                                                 \
      SET[q] = *(const float4*)(aRow + (size_t)q * 8 * HIDDEN + (COL));         \
  } while (0)
#define BLD(SET, COL) do { _Pragma("unroll")                                    \
    for (int p = 0; p < 2; ++p)                                                 \
      SET[p] = *(const bf16x8*)(bRow + (size_t)p * 16 * HIDDEN + (COL));        \
  } while (0)
#define AWR(SET, BUF, KK) do { _Pragma("unroll")                                \
    for (int q = 0; q < 4; ++q) {                                               \
      uint2 u;                                                                  \
      u.x = cvtpk(SET[q].x, SET[q].y);                                          \
      u.y = cvtpk(SET[q].z, SET[q].w);                                          \
      *(uint2*)(Alds + (BUF) * 16384 + (KK) * 8192 + aw0 + q * 256) = u;        \
      sq[q]  += SET[q].x + SET[q].y + SET[q].z + SET[q].w;                      \
      s2q[q] += SET[q].x * SET[q].x + SET[q].y * SET[q].y                       \
              + SET[q].z * SET[q].z + SET[q].w * SET[q].w;                      \
    }                                                                           \
  } while (0)
#define BWR(SET, BUF, KK) do { _Pragma("unroll")                                \
    for (int p = 0; p < 2; ++p)                                                 \
      *(bf16x8*)(Blds + (BUF) * 16384 + (KK) * 8192 + bw0 + p * 512) = SET[p];  \
  } while (0)
#define RDA(SET, BUF, KK, MH) do { _Pragma("unroll")                            \
    for (int m = 0; m < 4; ++m)                                                 \
      SET[(MH) * 4 + m] = *(const bf16x8*)(Alds + (BUF) * 16384 + (KK) * 8192 + (rowA + (MH) * 64 + m * 16) * 32 + rdx); \
  } while (0)
#define RDB(SET, BUF, KK) do { _Pragma("unroll")                                \
    for (int n = 0; n < 4; ++n)                                                 \
      SET[n] = *(const bf16x8*)(Blds + (BUF) * 16384 + (KK) * 8192 + (rowB + n * 16) * 32 + rdx); \
  } while (0)
#define MMX(ASET, BSET, MH) do {                                                \
    __builtin_amdgcn_s_setprio(1);                                              \
    _Pragma("unroll") for (int m = 0; m < 4; ++m)                               \
      _Pragma("unroll") for (int n = 0; n < 4; ++n)                             \
        acc[(MH) * 4 + m][n] = __builtin_amdgcn_mfma_f32_16x16x32_bf16(ASET[(MH) * 4 + m], BSET[n], acc[(MH) * 4 + m][n], 0, 0, 0); \
    __builtin_amdgcn_s_setprio(0);                                              \
  } while (0)
#define PIN __builtin_amdgcn_sched_barrier(0)
#define ENDPH do {                                                              \
    asm volatile("s_waitcnt lgkmcnt(0)" ::: "memory");                          \
    PIN; __builtin_amdgcn_s_barrier(); PIN;                                     \
  } while (0)

  // ---- prologue: write regions (0,0)(0,1)<-tile0, (1,0)(1,1)<-tile1;
  // prime P0/P1's load-sets with tile2 region (0,0) = col 128.
  BLD(bA, 0);   ALD(xA, 0);
  BLD(bB, 32);  ALD(xB, 32);
  BWR(bA, 0, 0); AWR(xA, 0, 0);
  BWR(bB, 0, 1); AWR(xB, 0, 1);
  BLD(bA, 64);  ALD(xA, 64);
  BLD(bB, 96);  ALD(xB, 96);
  BWR(bA, 1, 0); AWR(xA, 1, 0);
  BWR(bB, 1, 1); AWR(xB, 1, 1);
  BLD(bA, 128); ALD(xA, 128);
  ENDPH;                       // publish tiles 0,1
  RDA(a0, 0, 0, 0); RDB(b0, 0, 0);
  ENDPH;                       // R11 race fix: reads drained before P0 writes

  // ---- main loop: iters 0..5 full; iter 6 skips P6/P7 loads (tile 16 OOB);
  // iter 7 = pure-compute tail.
#define PH0(CB)  BWR(bA, 0, 0); if (CB) BLD(bB, CB);       RDA(a1, 0, 0, 1);                  PIN; MMX(a0, b0, 0); ENDPH
#define PH1(CA)  AWR(xA, 0, 0); if (CA) ALD(xB, CA);       RDA(a0, 0, 1, 0); RDB(b1, 0, 1);   PIN; MMX(a1, b0, 1); ENDPH
#define PH2(CB)  BWR(bB, 0, 1); if (CB) BLD(bA, CB);       RDA(a1, 0, 1, 1);                  PIN; MMX(a0, b1, 0); ENDPH
#define PH3(CA)  AWR(xB, 0, 1); if (CA) ALD(xA, CA);       RDA(a0, 1, 0, 0); RDB(b0, 1, 0);   PIN; MMX(a1, b1, 1); ENDPH
#define PH4(CB)  BWR(bA, 1, 0); if (CB) BLD(bB, CB);       RDA(a1, 1, 0, 1);                  PIN; MMX(a0, b0, 0); ENDPH
#define PH5(CA)  AWR(xA, 1, 0); if (CA) ALD(xB, CA);       RDA(a0, 1, 1, 0); RDB(b1, 1, 1);   PIN; MMX(a1, b0, 1); ENDPH
#define PH6(CB)  BWR(bB, 1, 1); if (CB) BLD(bA, CB);       RDA(a1, 1, 1, 1);                  PIN; MMX(a0, b1, 0); ENDPH
#define PH7(CA)  AWR(xB, 1, 1); if (CA) ALD(xA, CA);       RDA(a0, 0, 0, 0); RDB(b0, 0, 0);   PIN; MMX(a1, b1, 1); ENDPH

  for (int i = 0; i < 6; ++i) {
    const int T = 2 * i;
    PH0((T + 2) * 64 + 32);
    PH1((T + 2) * 64 + 32);
    PH2((T + 3) * 64);
    PH3((T + 3) * 64);
    PH4((T + 3) * 64 + 32);
    PH5((T + 3) * 64 + 32);
    PH6((T + 4) * 64);
    PH7((T + 4) * 64);
  }
  {  // iter 6 (T=12): writes tiles 14,15; no loads for tile 16.
    PH0(14 * 64 + 32);
    PH1(14 * 64 + 32);
    PH2(15 * 64);
    PH3(15 * 64);
    PH4(15 * 64 + 32);
    PH5(15 * 64 + 32);
    PH6(0);
    PH7(0);
  }
  // iter 7 (tiles 14,15): pure compute.
  RDA(a1, 0, 0, 1);                  PIN; MMX(a0, b0, 0); ENDPH;
  RDA(a0, 0, 1, 0); RDB(b1, 0, 1);   PIN; MMX(a1, b0, 1); ENDPH;
  RDA(a1, 0, 1, 1);                  PIN; MMX(a0, b1, 0); ENDPH;
  RDA(a0, 1, 0, 0); RDB(b0, 1, 0);   PIN; MMX(a1, b1, 1); ENDPH;
  RDA(a1, 1, 0, 1);                  PIN; MMX(a0, b0, 0); ENDPH;
  RDA(a0, 1, 1, 0); RDB(b1, 1, 1);   PIN; MMX(a1, b0, 1); ENDPH;
  RDA(a1, 1, 1, 1);                  PIN; MMX(a0, b1, 0); ENDPH;
  MMX(a1, b1, 1);

  // ---- stats: reduce (s,s2) across the 8 lanes sharing each row; publish.
#pragma unroll
  for (int q = 0; q < 4; ++q) {
#pragma unroll
    for (int off = 1; off <= 4; off <<= 1) {
      sq[q]  += __shfl_xor(sq[q],  off);
      s2q[q] += __shfl_xor(s2q[q], off);
    }
    if ((lane & 7) == 0)
      statsL[32 * w + q * 8 + (lane >> 3)] = make_float2(sq[q], s2q[q]);
  }
  asm volatile("s_waitcnt lgkmcnt(0)" ::: "memory");
  PIN; __builtin_amdgcn_s_barrier(); PIN;

#undef PH0
#undef PH1
#undef PH2
#undef PH3
#undef PH4
#undef PH5
#undef PH6
#undef PH7
#undef ALD
#undef BLD
#undef AWR
#undef BWR
#undef RDA
#undef RDB
#undef MMX
#undef ENDPH

  // ---- epilogue (R9-proven layout + LN fold): out = rstd*(acc - mu*c1) + c2 + b
  float* ep = (float*)Alds;               // 8 waves x 16 x 84 f32
  const int epb = w * 1344;
  const int headcol = segcol + wn * 64;
  const int gidx = headcol >> 6;
  const int tok0 = brow + wm * 128;
  const int b_ = tok0 >> 12;
  float* wout = out + obase + (size_t)(b_ * hg + gidx) * 262144u
                    + (size_t)(tok0 & 4095) * 64u;
  float c1v[4], cb2[4];
#pragma unroll
  for (int n = 0; n < 4; ++n) {
    const int hc = headcol + n * 16 + l15;
    c1v[n] = c1g[nbase + hc];
    cb2[n] = c2g[nbase + hc] + biasptr[hc];
  }

#pragma unroll
  for (int m = 0; m < 8; ++m) {
#pragma unroll
    for (int j = 0; j < 4; ++j) {
      const int row256 = wm * 128 + m * 16 + hi * 4 + j;
      const float2 st = statsL[row256];
      const float mu   = st.x * (1.0f / HIDDEN);
      const float rstd = rsqrtf(st.y * (1.0f / HIDDEN) - mu * mu + 1e-5f);
#pragma unroll
      for (int n = 0; n < 4; ++n)
        ep[epb + (hi * 4 + j) * 84 + n * 16 + l15] =
            rstd * (acc[m][n][j] - mu * c1v[n]) + cb2[n];
    }
    asm volatile("s_waitcnt lgkmcnt(0)" ::: "memory");
#pragma unroll
    for (int it = 0; it < 4; ++it) {
      const int r = it * 4 + hi;
      const float4 v = *(const float4*)(ep + epb + r * 84 + l15 * 4);
      *(float4*)(wout + (size_t)(m * 16 + r) * 64 + l15 * 4) = v;
    }
  }
#undef PIN
}

extern "C" void kernel_launch(void* const* d_in, const int* in_sizes, int n_in,
                              void* d_out, int out_size, void* d_ws, size_t ws_size,
                              hipStream_t stream) {
  const float* x  = (const float*)d_in[0];
  const float* wq = (const float*)d_in[1];
  const float* wk = (const float*)d_in[2];
  const float* wv = (const float*)d_in[3];
  const float* bq = (const float*)d_in[4];
  const float* bk = (const float*)d_in[5];
  const float* bv = (const float*)d_in[6];
  const float* g  = (const float*)d_in[7];
  const float* be = (const float*)d_in[8];
  float* out = (float*)d_out;

  unsigned short* wb = (unsigned short*)d_ws;                       // 3 MiB
  float* c1 = (float*)((char*)d_ws + (4u << 20));                   // 6 KiB
  float* c2 = c1 + 1536;

  cvt_c12<<<1536, 256, 0, stream>>>(wq, wk, wv, g, be, wb, c1, c2);
  qkv_gemm<<<768, 512, 0, stream>>>(x, wb, c1, c2, bq, bk, bv, out);
}

// Round 19
// 511.021 us; speedup vs baseline: 1.5667x; 1.5667x over previous
//
#include <hip/hip_runtime.h>
#include <hip/hip_bf16.h>

// InputProjection: LN folded INTO the GEMM (fp32 in, fp32 out).
// q = rstd*(x @ (gamma.*W)^T) - (rstd*mu)*c1 + (c2 + b).
// R19 = R18's algebra (HW-verified) with spill-free staging:
//   B: global_load_lds (R11-proven, 0 registers).
//   A: single xA[4] reg-stage, same-phase T14 split (ALD -> MFMA -> AWR);
//      AWR's implicit vmcnt drains the earlier-issued STB too -> no manual
//      vmcnt. Non-pipelined frags a[8],b[4]. ~105 VGPR + 128 AGPR <= 256.
// 256^2 tile, 8 waves, [2buf][2kk] regions, distance-1 staging, 32 phases.

#define HIDDEN 1024
#define NTOK   32768

typedef __bf16 bf16x8 __attribute__((ext_vector_type(8)));
typedef float  f32x4  __attribute__((ext_vector_type(4)));

#define GLOBAL_AS(p) ((const __attribute__((address_space(1))) void*)(p))
#define LDS_AS(p)    ((__attribute__((address_space(3))) void*)(p))

__device__ __forceinline__ float bf2f(unsigned short u) {
  union { unsigned int i; float f; } x; x.i = ((unsigned int)u) << 16; return x.f;
}
__device__ __forceinline__ unsigned short f2bf(float f) {
  union { float f; unsigned int i; } x; x.f = f;
  unsigned int r = x.i + 0x7FFFu + ((x.i >> 16) & 1u);   // RNE
  return (unsigned short)(r >> 16);
}
__device__ __forceinline__ unsigned int cvtpk(float lo, float hi) {
  unsigned int r;
  asm volatile("v_cvt_pk_bf16_f32 %0, %1, %2" : "=v"(r) : "v"(lo), "v"(hi));
  return r;
}

// ---------------- K1: gamma-folded weight cvt + c1/c2 (R18-proven) ----------------
__global__ __launch_bounds__(256) void cvt_c12(
    const float* __restrict__ wq, const float* __restrict__ wk,
    const float* __restrict__ wv, const float* __restrict__ gamma,
    const float* __restrict__ beta, unsigned short* __restrict__ wb,
    float* __restrict__ c1, float* __restrict__ c2) {
  const int n = blockIdx.x, t = threadIdx.x;
  const float* src; int roff;
  if (n < 1024)      { src = wq; roff = n; }
  else if (n < 1280) { src = wk; roff = n - 1024; }
  else               { src = wv; roff = n - 1280; }
  const float4 w4 = ((const float4*)(src + (size_t)roff * HIDDEN))[t];
  const float4 g4 = ((const float4*)gamma)[t];
  const float4 b4 = ((const float4*)beta)[t];
  ushort4 o;
  o.x = f2bf(w4.x * g4.x); o.y = f2bf(w4.y * g4.y);
  o.z = f2bf(w4.z * g4.z); o.w = f2bf(w4.w * g4.w);
  ((ushort4*)(wb + (size_t)n * HIDDEN))[t] = o;
  float c1p = bf2f(o.x) + bf2f(o.y) + bf2f(o.z) + bf2f(o.w);
  float c2p = b4.x * w4.x + b4.y * w4.y + b4.z * w4.z + b4.w * w4.w;
#pragma unroll
  for (int off = 32; off >= 1; off >>= 1) {
    c1p += __shfl_xor(c1p, off);
    c2p += __shfl_xor(c2p, off);
  }
  __shared__ float red[8];
  const int w = t >> 6;
  if ((t & 63) == 0) { red[w] = c1p; red[4 + w] = c2p; }
  __syncthreads();
  if (t == 0) {
    c1[n] = red[0] + red[1] + red[2] + red[3];
    c2[n] = red[4] + red[5] + red[6] + red[7];
  }
}

// ---------------- K2: fused LN+QKV GEMM ----------------
// 768 blocks (128 M x 6 N), 512 threads (8 waves, 2M x 4N), wave tile 128x64.
__global__ __launch_bounds__(512, 2) void qkv_gemm(
    const float* __restrict__ x,
    const unsigned short* __restrict__ wqb,
    const float* __restrict__ c1g,
    const float* __restrict__ c2g,
    const float* __restrict__ bq,
    const float* __restrict__ bk,
    const float* __restrict__ bv,
    float* __restrict__ out) {
  __shared__ unsigned short Alds[32768];   // [2buf][2kk][256][32] bf16
  __shared__ unsigned short Blds[32768];
  __shared__ float2 statsL[256];

  const int bid = blockIdx.x;
  const int swz = (bid & 7) * 96 + (bid >> 3);   // bijective: 768 % 8 == 0
  const int mt  = swz / 6;
  const int nt  = swz % 6;
  const int brow = mt * 256;

  const unsigned short* wbase; const float* biasptr;
  int segcol; size_t obase; int hg; int nbase;
  if (nt < 4)       { wbase = wqb + (size_t)nt * 256 * HIDDEN;  biasptr = bq; segcol = nt * 256; obase = 0u;        hg = 16; nbase = 0; }
  else if (nt == 4) { wbase = wqb + (size_t)1024 * HIDDEN;      biasptr = bk; segcol = 0;        obase = 33554432u; hg = 4;  nbase = 1024; }
  else              { wbase = wqb + (size_t)1280 * HIDDEN;      biasptr = bv; segcol = 0;        obase = 41943040u; hg = 4;  nbase = 1280; }

  const int t = threadIdx.x;
  const int w = t >> 6, lane = t & 63;
  const int wm = w >> 2, wn = w & 3;
  const int l15 = lane & 15, hi = lane >> 4;

  // B staging (R11-proven): wave w rows 32w..32w+31; granule (lane&3)^((row>>1)&3)
  const int sr  = 2 * w * 16 + (lane >> 2);
  const int scg = ((lane & 3) ^ ((lane >> 3) & 3)) * 8;
  const unsigned short* bST = wbase + (size_t)sr * HIDDEN + scg;
  const int ldsq = 2 * w * 512;

  // A reg-stage: lane covers rows 32w + q*8 + (lane>>3), cols (lane&7)*4..+4
  const float* aRow = x + (size_t)(brow + 32 * w + (lane >> 3)) * HIDDEN + (lane & 7) * 4;
  const int aw0 = (32 * w + (lane >> 3)) * 32
                + ((((lane & 7) >> 1) ^ (lane >> 4)) * 8) + (lane & 1) * 4;

  // ds_read (R11-proven): addr = buf*16384 + kk*8192 + row*32 + (hi^((row>>1)&3))*8
  const int rdx  = (hi ^ ((l15 >> 1) & 3)) * 8;
  const int rowA = wm * 128 + l15;
  const int rowB = wn * 64  + l15;

  f32x4 acc[8][4];
#pragma unroll
  for (int m = 0; m < 8; ++m)
#pragma unroll
    for (int n = 0; n < 4; ++n) acc[m][n] = (f32x4){0.f, 0.f, 0.f, 0.f};
  bf16x8 a[8], b[4];
  float4 xA[4];
  float sq[4]  = {0.f, 0.f, 0.f, 0.f};
  float s2q[4] = {0.f, 0.f, 0.f, 0.f};

#define STB(BUF, KK, KT) do {                                                   \
    unsigned short* _d = Blds + (BUF) * 16384 + (KK) * 8192 + ldsq;             \
    const unsigned short* _s = bST + (size_t)((KT) * 64 + (KK) * 32);           \
    __builtin_amdgcn_global_load_lds(GLOBAL_AS(_s), LDS_AS(_d), 16, 0, 0);      \
    __builtin_amdgcn_global_load_lds(GLOBAL_AS(_s + 16 * HIDDEN), LDS_AS(_d + 512), 16, 0, 0); \
  } while (0)
#define ALD(COL) do { _Pragma("unroll")                                         \
    for (int q = 0; q < 4; ++q)                                                 \
      xA[q] = *(const float4*)(aRow + (size_t)q * 8 * HIDDEN + (COL));          \
  } while (0)
#define AWR(BUF, KK) do { _Pragma("unroll")                                     \
    for (int q = 0; q < 4; ++q) {                                               \
      uint2 u;                                                                  \
      u.x = cvtpk(xA[q].x, xA[q].y);                                            \
      u.y = cvtpk(xA[q].z, xA[q].w);                                            \
      *(uint2*)(Alds + (BUF) * 16384 + (KK) * 8192 + aw0 + q * 256) = u;        \
      sq[q]  += xA[q].x + xA[q].y + xA[q].z + xA[q].w;                          \
      s2q[q] += xA[q].x * xA[q].x + xA[q].y * xA[q].y                           \
              + xA[q].z * xA[q].z + xA[q].w * xA[q].w;                          \
    }                                                                           \
  } while (0)
#define RD(BUF, KK) do { _Pragma("unroll")                                      \
    for (int m = 0; m < 8; ++m)                                                 \
      a[m] = *(const bf16x8*)(Alds + (BUF) * 16384 + (KK) * 8192 + (rowA + m * 16) * 32 + rdx); \
    _Pragma("unroll")                                                           \
    for (int n = 0; n < 4; ++n)                                                 \
      b[n] = *(const bf16x8*)(Blds + (BUF) * 16384 + (KK) * 8192 + (rowB + n * 16) * 32 + rdx); \
  } while (0)
#define MMX do {                                                                \
    __builtin_amdgcn_s_setprio(1);                                              \
    _Pragma("unroll") for (int m = 0; m < 8; ++m)                               \
      _Pragma("unroll") for (int n = 0; n < 4; ++n)                             \
        acc[m][n] = __builtin_amdgcn_mfma_f32_16x16x32_bf16(a[m], b[n], acc[m][n], 0, 0, 0); \
    __builtin_amdgcn_s_setprio(0);                                              \
  } while (0)
#define PIN __builtin_amdgcn_sched_barrier(0)
#define LGKM0 asm volatile("s_waitcnt lgkmcnt(0)" ::: "memory")
#define BAR __builtin_amdgcn_s_barrier()

// Phase (tile T parity BR, kk): stage tile KTN=T+1 (parity BW) same kk.
// AWR after MMX: its implicit vmcnt wait (xA use) drains ALD + earlier STBs;
// HBM latency hides under RD+MFMA. ds_writes drain at the closing LGKM0.
#define PH_S(BR, BW, KK, KTN) do {                                              \
    STB(BW, KK, KTN);                                                           \
    ALD((KTN) * 64 + (KK) * 32);                                                \
    RD(BR, KK);                                                                 \
    LGKM0; PIN;                                                                 \
    MMX;                                                                        \
    PIN;                                                                        \
    AWR(BW, KK);                                                                \
    LGKM0; PIN; BAR; PIN;                                                       \
  } while (0)
#define PH_N(BR, KK) do {                                                       \
    RD(BR, KK);                                                                 \
    LGKM0; PIN;                                                                 \
    MMX;                                                                        \
  } while (0)

  // prologue: tile 0 -> buf0 (B via gload_lds, A via reg-stage).
  STB(0, 0, 0); STB(0, 1, 0);
  ALD(0);  AWR(0, 0);
  ALD(32); AWR(0, 1);
  asm volatile("s_waitcnt vmcnt(0)" ::: "memory");   // reorder-proof: STBs landed
  LGKM0; PIN; BAR; PIN;

  for (int i = 0; i < 7; ++i) {
    const int T = 2 * i;
    PH_S(0, 1, 0, T + 1); PH_S(0, 1, 1, T + 1);   // read t(2i)   / stage t(2i+1)
    PH_S(1, 0, 0, T + 2); PH_S(1, 0, 1, T + 2);   // read t(2i+1) / stage t(2i+2)
  }
  // T=14: read buf0, stage t15 -> buf1 (explicit vmcnt(0) before last barrier:
  // guarantees STB(t15,kk1) landed even if compiler reordered it after ALD).
  PH_S(0, 1, 0, 15);
  STB(1, 1, 15);
  ALD(15 * 64 + 32);
  RD(0, 1);
  LGKM0; PIN;
  MMX;
  PIN;
  AWR(1, 1);
  asm volatile("s_waitcnt vmcnt(0)" ::: "memory");
  LGKM0; PIN; BAR; PIN;
  // T=15: read buf1, no staging.
  PH_N(1, 0);
  PH_N(1, 1);

  // stats: reduce (s,s2) over the 8 lanes sharing each row; publish to LDS.
#pragma unroll
  for (int q = 0; q < 4; ++q) {
#pragma unroll
    for (int off = 1; off <= 4; off <<= 1) {
      sq[q]  += __shfl_xor(sq[q],  off);
      s2q[q] += __shfl_xor(s2q[q], off);
    }
    if ((lane & 7) == 0)
      statsL[32 * w + q * 8 + (lane >> 3)] = make_float2(sq[q], s2q[q]);
  }
  LGKM0; PIN; BAR; PIN;

#undef STB
#undef ALD
#undef AWR
#undef RD
#undef MMX
#undef PH_S
#undef PH_N

  // ---- epilogue (R18-proven): out = rstd*(acc - mu*c1) + c2 + bias ----
  float* ep = (float*)Alds;               // 8 waves x 16 x 84 f32
  const int epb = w * 1344;
  const int headcol = segcol + wn * 64;
  const int gidx = headcol >> 6;
  const int tok0 = brow + wm * 128;
  const int b_ = tok0 >> 12;
  float* wout = out + obase + (size_t)(b_ * hg + gidx) * 262144u
                    + (size_t)(tok0 & 4095) * 64u;
  float c1v[4], cb2[4];
#pragma unroll
  for (int n = 0; n < 4; ++n) {
    const int hc = headcol + n * 16 + l15;
    c1v[n] = c1g[nbase + hc];
    cb2[n] = c2g[nbase + hc] + biasptr[hc];
  }

#pragma unroll
  for (int m = 0; m < 8; ++m) {
#pragma unroll
    for (int j = 0; j < 4; ++j) {
      const int row256 = wm * 128 + m * 16 + hi * 4 + j;
      const float2 st = statsL[row256];
      const float mu   = st.x * (1.0f / HIDDEN);
      const float rstd = rsqrtf(st.y * (1.0f / HIDDEN) - mu * mu + 1e-5f);
#pragma unroll
      for (int n = 0; n < 4; ++n)
        ep[epb + (hi * 4 + j) * 84 + n * 16 + l15] =
            rstd * (acc[m][n][j] - mu * c1v[n]) + cb2[n];
    }
    LGKM0;
#pragma unroll
    for (int it = 0; it < 4; ++it) {
      const int r = it * 4 + hi;
      const float4 v = *(const float4*)(ep + epb + r * 84 + l15 * 4);
      *(float4*)(wout + (size_t)(m * 16 + r) * 64 + l15 * 4) = v;
    }
  }
#undef PIN
#undef LGKM0
#undef BAR
}

extern "C" void kernel_launch(void* const* d_in, const int* in_sizes, int n_in,
                              void* d_out, int out_size, void* d_ws, size_t ws_size,
                              hipStream_t stream) {
  const float* x  = (const float*)d_in[0];
  const float* wq = (const float*)d_in[1];
  const float* wk = (const float*)d_in[2];
  const float* wv = (const float*)d_in[3];
  const float* bq = (const float*)d_in[4];
  const float* bk = (const float*)d_in[5];
  const float* bv = (const float*)d_in[6];
  const float* g  = (const float*)d_in[7];
  const float* be = (const float*)d_in[8];
  float* out = (float*)d_out;

  unsigned short* wb = (unsigned short*)d_ws;                       // 3 MiB
  float* c1 = (float*)((char*)d_ws + (4u << 20));                   // 6 KiB
  float* c2 = c1 + 1536;

  cvt_c12<<<1536, 256, 0, stream>>>(wq, wk, wv, g, be, wb, c1, c2);
  qkv_gemm<<<768, 512, 0, stream>>>(x, wb, c1, c2, bq, bk, bv, out);
}

// Round 20
// 171.333 us; speedup vs baseline: 4.6728x; 2.9826x over previous
//
#include <hip/hip_runtime.h>
#include <hip/hip_bf16.h>

// InputProjection: shared LayerNorm + Q/K/V projections (fp32 in, fp32 out).
// R20: two-pass (R12's ln_cvt) + epilogue-overlap GEMM. 128x256 tile, 4 waves
// (wave 64x128: acc[4][8]=128 AGPR + ~90 VGPR = fits 2 waves/SIMD), 72 KB LDS
// (3 regions, BK=32) -> launch_bounds(256,2) = 2 blocks/CU: one block's
// epilogue write-drain overlaps the other's K-loop (the ~10us/block serial
// term in R11). Protocol = R16's proven distance-2 staging with counted
// vmcnt(6); staging/ds_read swizzle = R11-proven; epilogue = R14-proven.

#define HIDDEN 1024
#define NTOK   32768

typedef __bf16 bf16x8 __attribute__((ext_vector_type(8)));
typedef float  f32x4  __attribute__((ext_vector_type(4)));

#define GLOBAL_AS(p) ((const __attribute__((address_space(1))) void*)(p))
#define LDS_AS(p)    ((__attribute__((address_space(3))) void*)(p))

__device__ __forceinline__ unsigned short f2bf(float f) {
  union { float f; unsigned int i; } x; x.f = f;
  unsigned int r = x.i + 0x7FFFu + ((x.i >> 16) & 1u);   // RNE
  return (unsigned short)(r >> 16);
}

// ---------------- K1: LayerNorm (fp32 in, bf16 out) + weight cvt (R12-proven) ----------------
__global__ __launch_bounds__(256) void ln_cvt_kernel(
    const float* __restrict__ x,
    const float* __restrict__ gamma,
    const float* __restrict__ beta,
    const float* __restrict__ wq,
    const float* __restrict__ wk,
    const float* __restrict__ wv,
    unsigned short* __restrict__ xn,
    unsigned short* __restrict__ wb) {
  const int bid = blockIdx.x;
  const int t   = threadIdx.x;
  if (bid < NTOK) {
    const size_t base = (size_t)bid * HIDDEN;
    const float4 v = ((const float4*)(x + base))[t];
    float s  = v.x + v.y + v.z + v.w;
    float s2 = v.x*v.x + v.y*v.y + v.z*v.z + v.w*v.w;
#pragma unroll
    for (int off = 32; off >= 1; off >>= 1) {
      s  += __shfl_xor(s,  off);
      s2 += __shfl_xor(s2, off);
    }
    __shared__ float red[8];
    const int w = t >> 6;
    if ((t & 63) == 0) { red[w] = s; red[4 + w] = s2; }
    __syncthreads();
    s  = red[0] + red[1] + red[2] + red[3];
    s2 = red[4] + red[5] + red[6] + red[7];
    const float mu   = s * (1.0f / HIDDEN);
    const float rstd = rsqrtf(s2 * (1.0f / HIDDEN) - mu * mu + 1e-5f);
    const float4 g  = ((const float4*)gamma)[t];
    const float4 bb = ((const float4*)beta)[t];
    ushort4 o;
    o.x = f2bf((v.x - mu) * rstd * g.x + bb.x);
    o.y = f2bf((v.y - mu) * rstd * g.y + bb.y);
    o.z = f2bf((v.z - mu) * rstd * g.z + bb.z);
    o.w = f2bf((v.w - mu) * rstd * g.w + bb.w);
    ((ushort4*)(xn + base))[t] = o;
  } else {
    const int b2 = bid - NTOK;           // 0..1535; 1024 wq, 256 wk, 256 wv
    const float* src;
    int off;
    if (b2 < 1024)      { src = wq; off = b2; }
    else if (b2 < 1280) { src = wk; off = b2 - 1024; }
    else                { src = wv; off = b2 - 1280; }
    const float4 v = ((const float4*)src)[off * 256 + t];
    ushort4 o;
    o.x = f2bf(v.x); o.y = f2bf(v.y); o.z = f2bf(v.z); o.w = f2bf(v.w);
    ((ushort4*)wb)[b2 * 256 + t] = o;
  }
}

// ---------------- K2: epilogue-overlap QKV GEMM ----------------
// 1536 blocks (256 M x 6 N, nt-major XCD swizzle), 256 threads (4 waves,
// 2M x 2N), wave tile 64x128 (2 heads). 2 blocks/CU.
__global__ __launch_bounds__(256, 2) void qkv_gemm(
    const unsigned short* __restrict__ xn,
    const unsigned short* __restrict__ wqb,
    const float* __restrict__ bq,
    const float* __restrict__ bk,
    const float* __restrict__ bv,
    float* __restrict__ out) {
  // A: [3 regions][128 rows][32 k] = 12288 u16 (24 KB);
  // B: [3 regions][256 rows][32 k] = 24576 u16 (48 KB). Total 72 KB.
  __shared__ unsigned short lds[36864];
  unsigned short* Alds = lds;
  unsigned short* Blds = lds + 12288;

  const int bid = blockIdx.x;
  const int swz = (bid & 7) * 192 + (bid >> 3);   // bijective: 1536 % 8 == 0
  const int mt  = swz & 255;                       // nt-major: B-panel L2-resident
  const int nt  = swz >> 8;
  const int brow = mt * 128;

  const unsigned short* wbase; const float* biasptr;
  int segcol; size_t obase; int hg;
  if (nt < 4)       { wbase = wqb + (size_t)nt * 256 * HIDDEN;  biasptr = bq; segcol = nt * 256; obase = 0u;        hg = 16; }
  else if (nt == 4) { wbase = wqb + (size_t)1024 * HIDDEN;      biasptr = bk; segcol = 0;        obase = 33554432u; hg = 4;  }
  else              { wbase = wqb + (size_t)1280 * HIDDEN;      biasptr = bv; segcol = 0;        obase = 41943040u; hg = 4;  }

  const int t = threadIdx.x;
  const int w = t >> 6, lane = t & 63;
  const int wm = w >> 1, wn = w & 1;               // wave tile: rows wm*64, cols wn*128
  const int l15 = lane & 15, hi = lane >> 4;

  // staging (R11-proven algebra): lane row = base + (lane>>2), granule
  // (lane&3)^((row>>1)&3). A: wave w covers rows w*32..+31 (2 instrs);
  // B: rows w*64..+63 (4 instrs).
  const int scg = ((lane & 3) ^ ((lane >> 3) & 3)) * 8;
  const unsigned short* aST = xn    + (size_t)(brow + w * 32 + (lane >> 2)) * HIDDEN + scg;
  const unsigned short* bST = wbase + (size_t)(w * 64 + (lane >> 2)) * HIDDEN + scg;
  const int aQ = w * 1024;    // wave-uniform LDS elems within region
  const int bQ = w * 2048;

  // ds_read (R11-proven): addr = regionOff + row*32 + (hi ^ ((row>>1)&3))*8
  const int rdx  = (hi ^ ((l15 >> 1) & 3)) * 8;
  const int rowA = wm * 64  + l15;
  const int rowB = wn * 128 + l15;

  f32x4 acc[4][8];
#pragma unroll
  for (int m = 0; m < 4; ++m)
#pragma unroll
    for (int n = 0; n < 8; ++n) acc[m][n] = (f32x4){0.f, 0.f, 0.f, 0.f};
  bf16x8 a[4], b[8];

#define ST(R, KT) do {                                                          \
    unsigned short* _da = Alds + (R) * 4096 + aQ;                               \
    unsigned short* _db = Blds + (R) * 8192 + bQ;                               \
    const unsigned short* _sa = aST + (size_t)((KT) * 32);                      \
    const unsigned short* _sb = bST + (size_t)((KT) * 32);                      \
    __builtin_amdgcn_global_load_lds(GLOBAL_AS(_sa), LDS_AS(_da), 16, 0, 0);    \
    __builtin_amdgcn_global_load_lds(GLOBAL_AS(_sa + 16 * HIDDEN), LDS_AS(_da + 512), 16, 0, 0); \
    _Pragma("unroll")                                                           \
    for (int i = 0; i < 4; ++i)                                                 \
      __builtin_amdgcn_global_load_lds(GLOBAL_AS(_sb + (size_t)i * 16 * HIDDEN), \
                                       LDS_AS(_db + i * 512), 16, 0, 0);        \
  } while (0)
#define RD(R) do { _Pragma("unroll")                                            \
    for (int m = 0; m < 4; ++m)                                                 \
      a[m] = *(const bf16x8*)(Alds + (R) * 4096 + (rowA + m * 16) * 32 + rdx);  \
    _Pragma("unroll")                                                           \
    for (int n = 0; n < 8; ++n)                                                 \
      b[n] = *(const bf16x8*)(Blds + (R) * 8192 + (rowB + n * 16) * 32 + rdx);  \
  } while (0)
#define MMX do {                                                                \
    __builtin_amdgcn_s_setprio(1);                                              \
    _Pragma("unroll") for (int m = 0; m < 4; ++m)                               \
      _Pragma("unroll") for (int n = 0; n < 8; ++n)                             \
        acc[m][n] = __builtin_amdgcn_mfma_f32_16x16x32_bf16(a[m], b[n], acc[m][n], 0, 0, 0); \
    __builtin_amdgcn_s_setprio(0);                                              \
  } while (0)
#define PIN __builtin_amdgcn_sched_barrier(0)
#define LGKM0 asm volatile("s_waitcnt lgkmcnt(0)" ::: "memory")
#define VMW(N) asm volatile("s_waitcnt vmcnt(" #N ")" ::: "memory")
#define BAR __builtin_amdgcn_s_barrier()

  // Phase T: {ST(T+2 -> region (T+2)%3); RD(region T%3); lgkm0; 32 MFMA;
  // vmcnt(6): own T+1 loads landed (T+2's 6 outstanding); barrier}.
  // WAR: ST(T+2) overwrites region (T-1)%3, whose reads drained at phase
  // T-1's lgkm0 before that barrier (R16-proven).
#define STEP(R, SR, T) do {                                                     \
    ST(SR, (T) + 2); RD(R); PIN; LGKM0; PIN; MMX;                               \
    VMW(6); PIN; BAR; PIN;                                                      \
  } while (0)

  // prologue: tiles 0,1 -> regions 0,1; validate tile 0 for all waves.
  ST(0, 0); ST(1, 1);
  VMW(6); PIN; BAR; PIN;

  for (int T = 0; T < 30; T += 3) {
    STEP(0, 2, T);
    STEP(1, 0, T + 1);
    STEP(2, 1, T + 2);
  }
  // T=30 (region 0): no stage; drain tile 31 fully.
  RD(0); PIN; LGKM0; PIN; MMX; VMW(0); PIN; BAR; PIN;
  // T=31 (region 1)
  RD(1); PIN; LGKM0; PIN; MMX;
  LGKM0; PIN; BAR; PIN;   // all reads done before epilogue reuses LDS

#undef ST
#undef RD
#undef MMX
#undef STEP

  // ---- epilogue (R14-proven): wave output = [64 tok][128 col] = 2 heads.
  // Per 16-token chunk: acc+bias -> LDS rows of 132 f32 -> float4 reads ->
  // 256B-contiguous stores per 16-lane group. Per-wave-disjoint LDS.
  float* ep = (float*)lds;               // 4 waves x 16 x 132 f32 = 33792 B
  const int epb = w * 2112;
  const int tok0 = brow + wm * 64;
  float biasv[8];
#pragma unroll
  for (int n = 0; n < 8; ++n) biasv[n] = biasptr[segcol + wn * 128 + n * 16 + l15];

#pragma unroll
  for (int m = 0; m < 4; ++m) {
#pragma unroll
    for (int n = 0; n < 8; ++n)
#pragma unroll
      for (int j = 0; j < 4; ++j)
        ep[epb + (hi * 4 + j) * 132 + n * 16 + l15] = acc[m][n][j] + biasv[n];
    LGKM0;
    PIN;
#pragma unroll
    for (int pass = 0; pass < 8; ++pass) {
      const int r = pass * 2 + (lane >> 5);
      const int c = (lane & 31) * 4;
      const float4 v = *(const float4*)(ep + epb + r * 132 + c);
      const int ncol = segcol + wn * 128 + c;
      const int g = ncol >> 6, d = ncol & 63;
      const int token = tok0 + m * 16 + r;
      const int b_ = token >> 12, s = token & 4095;
      *(float4*)(out + obase + (size_t)(b_ * hg + g) * 262144u
                     + (size_t)s * 64u + d) = v;
    }
  }
#undef PIN
#undef LGKM0
#undef VMW
#undef BAR
}

extern "C" void kernel_launch(void* const* d_in, const int* in_sizes, int n_in,
                              void* d_out, int out_size, void* d_ws, size_t ws_size,
                              hipStream_t stream) {
  const float* x  = (const float*)d_in[0];
  const float* wq = (const float*)d_in[1];
  const float* wk = (const float*)d_in[2];
  const float* wv = (const float*)d_in[3];
  const float* bq = (const float*)d_in[4];
  const float* bk = (const float*)d_in[5];
  const float* bv = (const float*)d_in[6];
  const float* g  = (const float*)d_in[7];
  const float* be = (const float*)d_in[8];
  float* out = (float*)d_out;

  unsigned short* xn = (unsigned short*)d_ws;                          // 64 MiB
  unsigned short* wb = (unsigned short*)((char*)d_ws + (64u << 20));   // 3 MiB

  ln_cvt_kernel<<<NTOK + 1536, 256, 0, stream>>>(x, g, be, wq, wk, wv, xn, wb);
  qkv_gemm<<<1536, 256, 0, stream>>>(xn, wb, bq, bk, bv, out);
}